// Round 5
// baseline (1706.496 us; speedup 1.0000x reference)
//
#include <hip/hip_runtime.h>
#include <cstdint>

#define Tn 200
#define En 512

// ---- embed gather for batch row 63 only ----
__global__ __launch_bounds__(128) void embed_k(const int* __restrict__ ids,
                                               const float* __restrict__ tab,
                                               float* __restrict__ x0) {
  const int t = blockIdx.x;
  const int e = threadIdx.x;
  const long id = ids[63 * Tn + t];
  const float4* src = (const float4*)(tab + (size_t)id * En);
  ((float4*)(x0 + (size_t)t * En))[e] = src[e];
}

// out[t][g] = (relu?)( A[t][:512] . W[g][:512] + bp1[g] + bp2?[g] )
__global__ __launch_bounds__(256) void gemm_rows(const float* __restrict__ A,
                                                 const float* __restrict__ W,
                                                 const float* __restrict__ bp1,
                                                 const float* __restrict__ bp2,
                                                 float* __restrict__ out,
                                                 int G, int relu) {
  __shared__ float xl[8 * 512];
  const int gr = blockIdx.x * 256 + threadIdx.x;
  const int t0 = blockIdx.y * 8;
  for (int i = threadIdx.x; i < 8 * 512; i += 256) xl[i] = A[(size_t)t0 * 512 + i];
  __syncthreads();
  const float b = bp1[gr] + (bp2 ? bp2[gr] : 0.f);
  float acc[8];
#pragma unroll
  for (int tt = 0; tt < 8; tt++) acc[tt] = b;
  const float4* wr = (const float4*)(W + (size_t)gr * 512);
  for (int k4 = 0; k4 < 128; k4++) {
    const float4 w = wr[k4];
#pragma unroll
    for (int tt = 0; tt < 8; tt++) {
      const float4 xv = *(const float4*)&xl[tt * 512 + k4 * 4];
      acc[tt] = fmaf(w.x, xv.x, fmaf(w.y, xv.y, fmaf(w.z, xv.z, fmaf(w.w, xv.w, acc[tt]))));
    }
  }
#pragma unroll
  for (int tt = 0; tt < 8; tt++) {
    float v = acc[tt];
    if (relu) v = fmaxf(v, 0.f);
    out[(size_t)(t0 + tt) * G + gr] = v;
  }
}

// ---- bidirectional LSTM recurrence, barrier-free wave-autonomous version ----
// 32 WGs x 512 threads: blocks 0-15 fwd, 16-31 bwd (independent sync domains).
// WG owns 16 h-elements; thread = (row=elem*4+gate, kc) holds 32 whh floats as
// 8 named float4s. NO __syncthreads in the loop: each WAVE privately stages the
// full 256-float h into its own LDS region (lane l polls slots 4l..4l+3 as 4
// independent pipelined agent loads, __all() vote, one float4 ds_write).
// Wave-internal lgkmcnt ordering replaces barriers; waves proceed the moment
// their data is ready (R4 floor was 2 barriers/step convoying 8 waves).
// Exchange slot: 8B = (stamp<<32)|float_bits, relaxed agent atomics.
__global__ __launch_bounds__(512, 2) void rec_k(const float* __restrict__ xp,   // [T][2048] fwd|bwd
                                                float* __restrict__ hcat,       // [T][512]
                                                unsigned long long* __restrict__ ex, // [T][512]
                                                const float* __restrict__ whh,  // dir-major 2*1024*256
                                                unsigned stampbase) {
  __shared__ float hs[8 * 288];  // per-wave 288-float region (stride-36 swizzle)
  const int tid = threadIdx.x;
  const int gb = blockIdx.x;
  const int dir = gb >> 4, wg = gb & 15;
  const int lane = tid & 63, w = tid >> 6;
  const int row = tid >> 3, kc = tid & 7;
  const int elem = row >> 2, gate = row & 3;
  const int he = wg * 16 + elem;        // global h element [0,256)
  const int gr = gate * 256 + he;       // gate row (i|f|g|o blocks of 256)
  const float* whhD = whh + (size_t)dir * 262144;
  const float* xpD = xp + dir * 1024;

  float4 q0, q1, q2, q3, q4, q5, q6, q7;
  {
    const float4* p = (const float4*)(whhD + (size_t)gr * 256 + kc * 32);
    q0 = p[0]; q1 = p[1]; q2 = p[2]; q3 = p[3];
    q4 = p[4]; q5 = p[5]; q6 = p[6]; q7 = p[7];
    asm volatile("" : "+v"(q0.x), "+v"(q0.y), "+v"(q0.z), "+v"(q0.w));
    asm volatile("" : "+v"(q1.x), "+v"(q1.y), "+v"(q1.z), "+v"(q1.w));
    asm volatile("" : "+v"(q2.x), "+v"(q2.y), "+v"(q2.z), "+v"(q2.w));
    asm volatile("" : "+v"(q3.x), "+v"(q3.y), "+v"(q3.z), "+v"(q3.w));
    asm volatile("" : "+v"(q4.x), "+v"(q4.y), "+v"(q4.z), "+v"(q4.w));
    asm volatile("" : "+v"(q5.x), "+v"(q5.y), "+v"(q5.z), "+v"(q5.w));
    asm volatile("" : "+v"(q6.x), "+v"(q6.y), "+v"(q6.z), "+v"(q6.w));
    asm volatile("" : "+v"(q7.x), "+v"(q7.y), "+v"(q7.z), "+v"(q7.w));
  }
  float* hw = &hs[w * 288];             // this wave's private h copy
  for (int i = lane; i < 288; i += 64) hw[i] = 0.f;
  float c = 0.f;
  float xv = 0.f;
  if (kc == 0) xv = xpD[(size_t)(dir ? (Tn - 1) : 0) * 2048 + gr];
  const int isprod = ((lane & 31) == 0);
  const int base = lane & 32;
  const int stoff = (lane >> 3) * 36 + 4 * (lane & 7);  // staging float4 offset
  asm volatile("s_waitcnt lgkmcnt(0)" ::: "memory");
  __builtin_amdgcn_sched_barrier(0);

  for (int t = 0; t < Tn; ++t) {
    // register matvec on this wave's private h(t-1)
    const float4* h4 = (const float4*)&hw[kc * 36];
    const float4 h0 = h4[0], h1 = h4[1], h2 = h4[2], h3 = h4[3];
    const float4 h5 = h4[4], h6 = h4[5], h7 = h4[6], h8 = h4[7];
    float a = 0.f;
    a = fmaf(q0.x, h0.x, a); a = fmaf(q0.y, h0.y, a); a = fmaf(q0.z, h0.z, a); a = fmaf(q0.w, h0.w, a);
    a = fmaf(q1.x, h1.x, a); a = fmaf(q1.y, h1.y, a); a = fmaf(q1.z, h1.z, a); a = fmaf(q1.w, h1.w, a);
    a = fmaf(q2.x, h2.x, a); a = fmaf(q2.y, h2.y, a); a = fmaf(q2.z, h2.z, a); a = fmaf(q2.w, h2.w, a);
    a = fmaf(q3.x, h3.x, a); a = fmaf(q3.y, h3.y, a); a = fmaf(q3.z, h3.z, a); a = fmaf(q3.w, h3.w, a);
    a = fmaf(q4.x, h5.x, a); a = fmaf(q4.y, h5.y, a); a = fmaf(q4.z, h5.z, a); a = fmaf(q4.w, h5.w, a);
    a = fmaf(q5.x, h6.x, a); a = fmaf(q5.y, h6.y, a); a = fmaf(q5.z, h6.z, a); a = fmaf(q5.w, h6.w, a);
    a = fmaf(q6.x, h7.x, a); a = fmaf(q6.y, h7.y, a); a = fmaf(q6.z, h7.z, a); a = fmaf(q6.w, h7.w, a);
    a = fmaf(q7.x, h8.x, a); a = fmaf(q7.y, h8.y, a); a = fmaf(q7.z, h8.z, a); a = fmaf(q7.w, h8.w, a);
    a += __shfl_xor(a, 1);
    a += __shfl_xor(a, 2);
    a += __shfl_xor(a, 4);
    if (kc == 0) a += xv;   // xproj (+biases) folded in by gemm_rows
    // gather the 4 gate sums of this wave's two elements to lanes 0 / 32
    const float gi = __shfl(a, base + 0);
    const float gf = __shfl(a, base + 8);
    const float gg = __shfl(a, base + 16);
    const float go = __shfl(a, base + 24);
    if (isprod) {
      const float iv = 1.f / (1.f + __expf(-gi));
      const float fv = 1.f / (1.f + __expf(-gf));
      const float gv = 1.f - 2.f / (1.f + __expf(2.f * gg));
      const float ov = 1.f / (1.f + __expf(-go));
      c = fv * c + iv * gv;
      const float hv = ov * (1.f - 2.f / (1.f + __expf(2.f * c)));
      // flag|data word first (critical path), bulk output second
      __hip_atomic_store(&ex[(size_t)t * 512 + dir * 256 + he],
                         ((unsigned long long)(stampbase + t + 1) << 32) | __float_as_uint(hv),
                         __ATOMIC_RELAXED, __HIP_MEMORY_SCOPE_AGENT);
      const int rowt = dir ? (Tn - 1 - t) : t;
      hcat[(size_t)rowt * 512 + dir * 256 + he] = hv;
    }
    if (t + 1 < Tn) {
      if (kc == 0)  // prefetch next step's xproj during the poll
        xv = xpD[(size_t)(dir ? (Tn - 2 - t) : (t + 1)) * 2048 + gr];
      // wave-private poll: lane l owns slots 4l..4l+3 (pipelined independent loads)
      const unsigned long long* sl = &ex[(size_t)t * 512 + dir * 256 + 4 * lane];
      const unsigned tgt = stampbase + (unsigned)t + 1u;
      unsigned long long v0, v1, v2, v3;
      int gd = 0;
      for (;;) {
        v0 = __hip_atomic_load(sl + 0, __ATOMIC_RELAXED, __HIP_MEMORY_SCOPE_AGENT);
        v1 = __hip_atomic_load(sl + 1, __ATOMIC_RELAXED, __HIP_MEMORY_SCOPE_AGENT);
        v2 = __hip_atomic_load(sl + 2, __ATOMIC_RELAXED, __HIP_MEMORY_SCOPE_AGENT);
        v3 = __hip_atomic_load(sl + 3, __ATOMIC_RELAXED, __HIP_MEMORY_SCOPE_AGENT);
        const bool ok = ((unsigned)(v0 >> 32) == tgt) & ((unsigned)(v1 >> 32) == tgt) &
                        ((unsigned)(v2 >> 32) == tgt) & ((unsigned)(v3 >> 32) == tgt);
        if (__all(ok) || ++gd >= (1 << 18)) break;
      }
      float4 hv4;
      hv4.x = __uint_as_float((unsigned)v0);
      hv4.y = __uint_as_float((unsigned)v1);
      hv4.z = __uint_as_float((unsigned)v2);
      hv4.w = __uint_as_float((unsigned)v3);
      *(float4*)&hw[stoff] = hv4;       // stage into OUR wave's region
      asm volatile("s_waitcnt lgkmcnt(0)" ::: "memory");
      __builtin_amdgcn_sched_barrier(0);
    }
  }
}

// ---- final 1024->7 matmul + softmax per timestep ----
__global__ __launch_bounds__(64) void mlp2_k(const float* __restrict__ h1,
                                             const float* __restrict__ w2,
                                             const float* __restrict__ b2,
                                             float* __restrict__ out) {
  __shared__ float hrow[1024];
  __shared__ float lg[8];
  const int t = blockIdx.x, tid = threadIdx.x;
  for (int i = tid; i < 1024; i += 64) hrow[i] = h1[(size_t)t * 1024 + i];
  __syncthreads();
  const int o = tid >> 3, kc = tid & 7;
  float acc = 0.f;
  if (o < 7) {
    const float* wv = w2 + (size_t)o * 1024 + kc * 128;
    const float* h = &hrow[kc * 128];
    for (int jj = 0; jj < 128; jj++) acc = fmaf(wv[jj], h[jj], acc);
  }
#pragma unroll
  for (int off = 1; off < 8; off <<= 1) acc += __shfl_xor(acc, off);
  if (o < 7 && kc == 0) lg[o] = acc + b2[o];
  __syncthreads();
  if (tid == 0) {
    float mx = -1e30f;
#pragma unroll
    for (int i = 0; i < 7; i++) mx = fmaxf(mx, lg[i]);
    float e[7];
    float s = 0.f;
#pragma unroll
    for (int i = 0; i < 7; i++) { e[i] = __expf(lg[i] - mx); s += e[i]; }
    const float inv = 1.f / s;
#pragma unroll
    for (int i = 0; i < 7; i++) out[t * 7 + i] = e[i] * inv;
  }
}

extern "C" void kernel_launch(void* const* d_in, const int* in_sizes, int n_in,
                              void* d_out, int out_size, void* d_ws, size_t ws_size,
                              hipStream_t stream) {
  const int* ids = (const int*)d_in[0];
  const float* tab = (const float*)d_in[1];
  const float* wih = (const float*)d_in[2];   // (2,2,1024,512)
  const float* whh = (const float*)d_in[3];   // (2,2,1024,256)
  const float* bih = (const float*)d_in[4];   // (2,2,1024)
  const float* bhh = (const float*)d_in[5];
  const float* w1 = (const float*)d_in[6];    // (1024,512)
  const float* b1 = (const float*)d_in[7];
  const float* w2 = (const float*)d_in[8];    // (7,1024)
  const float* b2 = (const float*)d_in[9];
  float* out = (float*)d_out;                 // (200,7) f32
  float* ws = (float*)d_ws;

  float* x0 = ws;                     // 200*512
  float* xp = ws + 102400;            // 200*2048 (reused both layers)
  float* h0 = ws + 512000;            // 200*512
  float* h1 = ws + 614400;            // 200*512
  float* hm = ws + 716800;            // 200*1024
  unsigned long long* ex = (unsigned long long*)(ws + 921600);  // 200*512 8B slots

  // clear stamps from previous replay (slots are write-once within a launch)
  hipMemsetAsync(ex, 0, (size_t)Tn * 512 * 8, stream);
  embed_k<<<Tn, 128, 0, stream>>>(ids, tab, x0);
  // layer 0
  gemm_rows<<<dim3(8, 25), 256, 0, stream>>>(x0, wih, bih, bhh, xp, 2048, 0);
  rec_k<<<32, 512, 0, stream>>>(xp, h0, ex, whh, 0u);
  // layer 1 (shared ex buffer, disjoint stamp base)
  gemm_rows<<<dim3(8, 25), 256, 0, stream>>>(h0, wih + 1048576, bih + 2048, bhh + 2048, xp, 2048, 0);
  rec_k<<<32, 512, 0, stream>>>(xp, h1, ex, whh + 524288, 1000000u);
  // MLP
  gemm_rows<<<dim3(4, 25), 256, 0, stream>>>(h1, w1, b1, nullptr, hm, 1024, 1);
  mlp2_k<<<Tn, 64, 0, stream>>>(hm, w2, b2, out);
}

// Round 6
// 1085.227 us; speedup vs baseline: 1.5725x; 1.5725x over previous
//
#include <hip/hip_runtime.h>
#include <cstdint>

#define Tn 200
#define En 512

// ---- embed gather for batch row 63 only ----
__global__ __launch_bounds__(128) void embed_k(const int* __restrict__ ids,
                                               const float* __restrict__ tab,
                                               float* __restrict__ x0) {
  const int t = blockIdx.x;
  const int e = threadIdx.x;
  const long id = ids[63 * Tn + t];
  const float4* src = (const float4*)(tab + (size_t)id * En);
  ((float4*)(x0 + (size_t)t * En))[e] = src[e];
}

// out[t][g] = (relu?)( A[t][:512] . W[g][:512] + bp1[g] + bp2?[g] )
__global__ __launch_bounds__(256) void gemm_rows(const float* __restrict__ A,
                                                 const float* __restrict__ W,
                                                 const float* __restrict__ bp1,
                                                 const float* __restrict__ bp2,
                                                 float* __restrict__ out,
                                                 int G, int relu) {
  __shared__ float xl[8 * 512];
  const int gr = blockIdx.x * 256 + threadIdx.x;
  const int t0 = blockIdx.y * 8;
  for (int i = threadIdx.x; i < 8 * 512; i += 256) xl[i] = A[(size_t)t0 * 512 + i];
  __syncthreads();
  const float b = bp1[gr] + (bp2 ? bp2[gr] : 0.f);
  float acc[8];
#pragma unroll
  for (int tt = 0; tt < 8; tt++) acc[tt] = b;
  const float4* wr = (const float4*)(W + (size_t)gr * 512);
  for (int k4 = 0; k4 < 128; k4++) {
    const float4 w = wr[k4];
#pragma unroll
    for (int tt = 0; tt < 8; tt++) {
      const float4 xv = *(const float4*)&xl[tt * 512 + k4 * 4];
      acc[tt] = fmaf(w.x, xv.x, fmaf(w.y, xv.y, fmaf(w.z, xv.z, fmaf(w.w, xv.w, acc[tt]))));
    }
  }
#pragma unroll
  for (int tt = 0; tt < 8; tt++) {
    float v = acc[tt];
    if (relu) v = fmaxf(v, 0.f);
    out[(size_t)(t0 + tt) * G + gr] = v;
  }
}

// ---- bidirectional LSTM recurrence: 1-wave LLC poll + LDS chunk flags ----
// 32 WGs x 512 thr: blocks 0-15 fwd, 16-31 bwd (independent sync domains).
// WG owns 16 h-elems = 64 gate rows. Weights live in LDS (72KB, stride-36,
// conflict-optimal b128). NO __syncthreads in loop:
//  - wave 0: lane l polls LLC slots 4l..4l+3 (8B stamp|data words), stages
//    each float4 into hs[(t+1)&1] AS IT ARRIVES, bumps LDS chunk counter;
//    8th arrival posts chunk flag cf[p][chunk]=t+1.
//  - all threads: spin on cf[t&1][kc] >= t (own chunk only), then matvec.
// Double-buffered hs is overwrite-safe by causality: any h(t) slot implies
// every wave finished reading hs for t-1.
__global__ __launch_bounds__(512, 2) void rec_k(const float* __restrict__ xp,   // [T][2048] fwd|bwd
                                                float* __restrict__ hcat,       // [T][512]
                                                unsigned long long* __restrict__ ex, // [T][512]
                                                const float* __restrict__ whh,  // dir-major 2*1024*256
                                                unsigned stampbase) {
  __shared__ __align__(16) float wlds[512 * 36];  // 73728 B
  __shared__ __align__(16) float hs[2][288];      // stride-36 chunks
  __shared__ unsigned cf[2][8];                   // chunk flags (stamps)
  __shared__ unsigned cnt[2][8];                  // chunk arrival counters
  __shared__ float pad2[1600];                    // pushes LDS >80KB: 1 WG/CU
  const int tid = threadIdx.x;
  const int gb = blockIdx.x;
  const int dir = gb >> 4, wg = gb & 15;
  const int lane = tid & 63, w = tid >> 6;
  const int row = tid >> 3, kc = tid & 7;
  const int elem = row >> 2, gate = row & 3;
  const int he = wg * 16 + elem;        // global h element [0,256)
  const int gr = gate * 256 + he;       // gate row (i|f|g|o blocks of 256)
  const float* whhD = whh + (size_t)dir * 262144;
  const float* xpD = xp + dir * 1024;

  if (stampbase == 0xDEADBEEFu) {  // never true; keeps pad2 allocated
    pad2[tid] = xp[tid];
    hcat[tid] = pad2[tid ^ 1];
  }
  // stage this thread's 32 weights into LDS (once)
  {
    const float4* src = (const float4*)(whhD + (size_t)gr * 256 + kc * 32);
    float4* dst = (float4*)&wlds[tid * 36];
#pragma unroll
    for (int m = 0; m < 8; m++) dst[m] = src[m];
  }
  if (tid < 16) { cf[tid >> 3][tid & 7] = 0u; cnt[tid >> 3][tid & 7] = 0u; }
  for (int i = tid; i < 2 * 288; i += 512) ((float*)hs)[i] = 0.f;
  float c = 0.f;
  float xv = 0.f;
  if (kc == 0) xv = xpD[(size_t)(dir ? (Tn - 1) : 0) * 2048 + gr];
  const int isprod = ((lane & 31) == 0);
  const int base = lane & 32;
  __syncthreads();  // one-time init barrier

  const float4* wq = (const float4*)&wlds[tid * 36];

  for (int t = 0; t < Tn; ++t) {
    const int p = t & 1;
    // wait for OUR chunk of h(t-1) (t=0 passes: cf init 0 >= 0)
    {
      const unsigned tgt = (unsigned)t;
      int gd = 0;
      while (__hip_atomic_load(&cf[p][kc], __ATOMIC_ACQUIRE, __HIP_MEMORY_SCOPE_WORKGROUP) < tgt
             && ++gd < (1 << 20)) {}
      asm volatile("s_waitcnt lgkmcnt(0)" ::: "memory");
      __builtin_amdgcn_sched_barrier(0);
    }
    // matvec: LDS weights x LDS h chunk
    const float4 q0 = wq[0], q1 = wq[1], q2 = wq[2], q3 = wq[3];
    const float4 q4 = wq[4], q5 = wq[5], q6 = wq[6], q7 = wq[7];
    const float4* h4 = (const float4*)&hs[p][kc * 36];
    const float4 h0 = h4[0], h1 = h4[1], h2 = h4[2], h3 = h4[3];
    const float4 h5 = h4[4], h6 = h4[5], h7 = h4[6], h8 = h4[7];
    float a = 0.f;
    a = fmaf(q0.x, h0.x, a); a = fmaf(q0.y, h0.y, a); a = fmaf(q0.z, h0.z, a); a = fmaf(q0.w, h0.w, a);
    a = fmaf(q1.x, h1.x, a); a = fmaf(q1.y, h1.y, a); a = fmaf(q1.z, h1.z, a); a = fmaf(q1.w, h1.w, a);
    a = fmaf(q2.x, h2.x, a); a = fmaf(q2.y, h2.y, a); a = fmaf(q2.z, h2.z, a); a = fmaf(q2.w, h2.w, a);
    a = fmaf(q3.x, h3.x, a); a = fmaf(q3.y, h3.y, a); a = fmaf(q3.z, h3.z, a); a = fmaf(q3.w, h3.w, a);
    a = fmaf(q4.x, h5.x, a); a = fmaf(q4.y, h5.y, a); a = fmaf(q4.z, h5.z, a); a = fmaf(q4.w, h5.w, a);
    a = fmaf(q5.x, h6.x, a); a = fmaf(q5.y, h6.y, a); a = fmaf(q5.z, h6.z, a); a = fmaf(q5.w, h6.w, a);
    a = fmaf(q6.x, h7.x, a); a = fmaf(q6.y, h7.y, a); a = fmaf(q6.z, h7.z, a); a = fmaf(q6.w, h7.w, a);
    a = fmaf(q7.x, h8.x, a); a = fmaf(q7.y, h8.y, a); a = fmaf(q7.z, h8.z, a); a = fmaf(q7.w, h8.w, a);
    a += __shfl_xor(a, 1);
    a += __shfl_xor(a, 2);
    a += __shfl_xor(a, 4);
    if (kc == 0) a += xv;   // xproj (+both biases) folded in by gemm_rows
    // gather the 4 gate sums of this wave's two elements to lanes 0 / 32
    const float gi = __shfl(a, base + 0);
    const float gf = __shfl(a, base + 8);
    const float gg = __shfl(a, base + 16);
    const float go = __shfl(a, base + 24);
    if (isprod) {
      const float iv = 1.f / (1.f + __expf(-gi));
      const float fv = 1.f / (1.f + __expf(-gf));
      const float gv = 1.f - 2.f / (1.f + __expf(2.f * gg));
      const float ov = 1.f / (1.f + __expf(-go));
      c = fv * c + iv * gv;
      const float hv = ov * (1.f - 2.f / (1.f + __expf(2.f * c)));
      __hip_atomic_store(&ex[(size_t)t * 512 + dir * 256 + he],
                         ((unsigned long long)(stampbase + t + 1) << 32) | __float_as_uint(hv),
                         __ATOMIC_RELAXED, __HIP_MEMORY_SCOPE_AGENT);
      const int rowt = dir ? (Tn - 1 - t) : t;
      hcat[(size_t)rowt * 512 + dir * 256 + he] = hv;
    }
    if (t + 1 < Tn) {
      if (kc == 0)  // prefetch next step's xproj (hidden under the wait)
        xv = xpD[(size_t)(dir ? (Tn - 2 - t) : (t + 1)) * 2048 + gr];
      if (w == 0) {
        // single-wave LLC poll; stage each float4 as it arrives
        const int pn = (t + 1) & 1;
        const unsigned long long* sl = &ex[(size_t)t * 512 + dir * 256 + 4 * lane];
        const unsigned tgt = stampbase + (unsigned)t + 1u;
        const int chunk = lane >> 3;
        float* dst = &hs[pn][chunk * 36 + 4 * (lane & 7)];
        bool pend = true;
        int gd = 0;
        while (__any(pend) && ++gd < (1 << 20)) {
          if (pend) {
            const unsigned long long v0 =
                __hip_atomic_load(sl + 0, __ATOMIC_RELAXED, __HIP_MEMORY_SCOPE_AGENT);
            const unsigned long long v1 =
                __hip_atomic_load(sl + 1, __ATOMIC_RELAXED, __HIP_MEMORY_SCOPE_AGENT);
            const unsigned long long v2 =
                __hip_atomic_load(sl + 2, __ATOMIC_RELAXED, __HIP_MEMORY_SCOPE_AGENT);
            const unsigned long long v3 =
                __hip_atomic_load(sl + 3, __ATOMIC_RELAXED, __HIP_MEMORY_SCOPE_AGENT);
            if (((unsigned)(v0 >> 32) == tgt) & ((unsigned)(v1 >> 32) == tgt) &
                ((unsigned)(v2 >> 32) == tgt) & ((unsigned)(v3 >> 32) == tgt)) {
              float4 hv4;
              hv4.x = __uint_as_float((unsigned)v0);
              hv4.y = __uint_as_float((unsigned)v1);
              hv4.z = __uint_as_float((unsigned)v2);
              hv4.w = __uint_as_float((unsigned)v3);
              *(float4*)dst = hv4;
              const unsigned old = __hip_atomic_fetch_add(&cnt[pn][chunk], 1u, __ATOMIC_RELEASE,
                                                          __HIP_MEMORY_SCOPE_WORKGROUP);
              if (old == 7u)  // last arrival of this chunk posts its flag
                __hip_atomic_store(&cf[pn][chunk], (unsigned)(t + 1), __ATOMIC_RELEASE,
                                   __HIP_MEMORY_SCOPE_WORKGROUP);
              pend = false;
            }
          }
        }
        if (lane < 8) cnt[pn][lane] = 0u;  // reset for this parity's next use (t+2)
      }
    }
  }
}

// ---- final 1024->7 matmul + softmax per timestep ----
__global__ __launch_bounds__(64) void mlp2_k(const float* __restrict__ h1,
                                             const float* __restrict__ w2,
                                             const float* __restrict__ b2,
                                             float* __restrict__ out) {
  __shared__ float hrow[1024];
  __shared__ float lg[8];
  const int t = blockIdx.x, tid = threadIdx.x;
  for (int i = tid; i < 1024; i += 64) hrow[i] = h1[(size_t)t * 1024 + i];
  __syncthreads();
  const int o = tid >> 3, kc = tid & 7;
  float acc = 0.f;
  if (o < 7) {
    const float* wv = w2 + (size_t)o * 1024 + kc * 128;
    const float* h = &hrow[kc * 128];
    for (int jj = 0; jj < 128; jj++) acc = fmaf(wv[jj], h[jj], acc);
  }
#pragma unroll
  for (int off = 1; off < 8; off <<= 1) acc += __shfl_xor(acc, off);
  if (o < 7 && kc == 0) lg[o] = acc + b2[o];
  __syncthreads();
  if (tid == 0) {
    float mx = -1e30f;
#pragma unroll
    for (int i = 0; i < 7; i++) mx = fmaxf(mx, lg[i]);
    float e[7];
    float s = 0.f;
#pragma unroll
    for (int i = 0; i < 7; i++) { e[i] = __expf(lg[i] - mx); s += e[i]; }
    const float inv = 1.f / s;
#pragma unroll
    for (int i = 0; i < 7; i++) out[t * 7 + i] = e[i] * inv;
  }
}

extern "C" void kernel_launch(void* const* d_in, const int* in_sizes, int n_in,
                              void* d_out, int out_size, void* d_ws, size_t ws_size,
                              hipStream_t stream) {
  const int* ids = (const int*)d_in[0];
  const float* tab = (const float*)d_in[1];
  const float* wih = (const float*)d_in[2];   // (2,2,1024,512)
  const float* whh = (const float*)d_in[3];   // (2,2,1024,256)
  const float* bih = (const float*)d_in[4];   // (2,2,1024)
  const float* bhh = (const float*)d_in[5];
  const float* w1 = (const float*)d_in[6];    // (1024,512)
  const float* b1 = (const float*)d_in[7];
  const float* w2 = (const float*)d_in[8];    // (7,1024)
  const float* b2 = (const float*)d_in[9];
  float* out = (float*)d_out;                 // (200,7) f32
  float* ws = (float*)d_ws;

  float* x0 = ws;                     // 200*512
  float* xp = ws + 102400;            // 200*2048 (reused both layers)
  float* h0 = ws + 512000;            // 200*512
  float* h1 = ws + 614400;            // 200*512
  float* hm = ws + 716800;            // 200*1024
  unsigned long long* ex = (unsigned long long*)(ws + 921600);  // 200*512 8B slots

  // clear stamps from previous replay (slots are write-once within a launch)
  hipMemsetAsync(ex, 0, (size_t)Tn * 512 * 8, stream);
  embed_k<<<Tn, 128, 0, stream>>>(ids, tab, x0);
  // layer 0
  gemm_rows<<<dim3(8, 25), 256, 0, stream>>>(x0, wih, bih, bhh, xp, 2048, 0);
  rec_k<<<32, 512, 0, stream>>>(xp, h0, ex, whh, 0u);
  // layer 1 (shared ex buffer, disjoint stamp base)
  gemm_rows<<<dim3(8, 25), 256, 0, stream>>>(h0, wih + 1048576, bih + 2048, bhh + 2048, xp, 2048, 0);
  rec_k<<<32, 512, 0, stream>>>(xp, h1, ex, whh + 524288, 1000000u);
  // MLP
  gemm_rows<<<dim3(4, 25), 256, 0, stream>>>(h1, w1, b1, nullptr, hm, 1024, 1);
  mlp2_k<<<Tn, 64, 0, stream>>>(hm, w2, b2, out);
}

// Round 7
// 853.675 us; speedup vs baseline: 1.9990x; 1.2712x over previous
//
#include <hip/hip_runtime.h>
#include <cstdint>

#define Tn 200
#define En 512

// ---- embed gather for batch row 63 only ----
__global__ __launch_bounds__(128) void embed_k(const int* __restrict__ ids,
                                               const float* __restrict__ tab,
                                               float* __restrict__ x0) {
  const int t = blockIdx.x;
  const int e = threadIdx.x;
  const long id = ids[63 * Tn + t];
  const float4* src = (const float4*)(tab + (size_t)id * En);
  ((float4*)(x0 + (size_t)t * En))[e] = src[e];
}

// out[t][g] = (relu?)( A[t][:512] . W[g][:512] + bp1[g] + bp2?[g] )
__global__ __launch_bounds__(256) void gemm_rows(const float* __restrict__ A,
                                                 const float* __restrict__ W,
                                                 const float* __restrict__ bp1,
                                                 const float* __restrict__ bp2,
                                                 float* __restrict__ out,
                                                 int G, int relu) {
  __shared__ float xl[8 * 512];
  const int gr = blockIdx.x * 256 + threadIdx.x;
  const int t0 = blockIdx.y * 8;
  for (int i = threadIdx.x; i < 8 * 512; i += 256) xl[i] = A[(size_t)t0 * 512 + i];
  __syncthreads();
  const float b = bp1[gr] + (bp2 ? bp2[gr] : 0.f);
  float acc[8];
#pragma unroll
  for (int tt = 0; tt < 8; tt++) acc[tt] = b;
  const float4* wr = (const float4*)(W + (size_t)gr * 512);
  for (int k4 = 0; k4 < 128; k4++) {
    const float4 w = wr[k4];
#pragma unroll
    for (int tt = 0; tt < 8; tt++) {
      const float4 xv = *(const float4*)&xl[tt * 512 + k4 * 4];
      acc[tt] = fmaf(w.x, xv.x, fmaf(w.y, xv.y, fmaf(w.z, xv.z, fmaf(w.w, xv.w, acc[tt]))));
    }
  }
#pragma unroll
  for (int tt = 0; tt < 8; tt++) {
    float v = acc[tt];
    if (relu) v = fmaxf(v, 0.f);
    out[(size_t)(t0 + tt) * G + gr] = v;
  }
}

// ---- bidirectional LSTM recurrence (R4 skeleton, single barrier/step) ----
// 32 WGs x 512 threads: blocks 0-15 fwd, 16-31 bwd (independent sync domains).
// WG owns 16 h-elems = 64 gate rows; thread holds 32 whh floats as 8 named
// float4s (VGPR-resident, proven R4). Exchange: 8B slot = (stamp<<32)|bits,
// relaxed agent atomics; 240 consumers poll ONE remote slot each; producers
// ds_write their own 16 elems locally. Double-buffered hs + ONE
// __syncthreads per step (R3/R4 had two).
__global__ __launch_bounds__(512, 2) void rec_k(const float* __restrict__ xp,   // [T][2048] fwd|bwd
                                                float* __restrict__ hcat,       // [T][512]
                                                unsigned long long* __restrict__ ex, // [T][512]
                                                const float* __restrict__ whh,  // dir-major 2*1024*256
                                                unsigned stampbase) {
  __shared__ __align__(16) float hs[2][288];  // stride-36 chunks, double buffer
  const int tid = threadIdx.x;
  const int gb = blockIdx.x;
  const int dir = gb >> 4, wg = gb & 15;
  const int lane = tid & 63;
  const int row = tid >> 3, kc = tid & 7;
  const int elem = row >> 2, gate = row & 3;
  const int he = wg * 16 + elem;        // global h element [0,256)
  const int gr = gate * 256 + he;       // gate row (i|f|g|o blocks of 256)
  const float* whhD = whh + (size_t)dir * 262144;
  const float* xpD = xp + dir * 1024;

  float4 q0, q1, q2, q3, q4, q5, q6, q7;
  {
    const float4* p = (const float4*)(whhD + (size_t)gr * 256 + kc * 32);
    q0 = p[0]; q1 = p[1]; q2 = p[2]; q3 = p[3];
    q4 = p[4]; q5 = p[5]; q6 = p[6]; q7 = p[7];
    asm volatile("" : "+v"(q0.x), "+v"(q0.y), "+v"(q0.z), "+v"(q0.w));
    asm volatile("" : "+v"(q1.x), "+v"(q1.y), "+v"(q1.z), "+v"(q1.w));
    asm volatile("" : "+v"(q2.x), "+v"(q2.y), "+v"(q2.z), "+v"(q2.w));
    asm volatile("" : "+v"(q3.x), "+v"(q3.y), "+v"(q3.z), "+v"(q3.w));
    asm volatile("" : "+v"(q4.x), "+v"(q4.y), "+v"(q4.z), "+v"(q4.w));
    asm volatile("" : "+v"(q5.x), "+v"(q5.y), "+v"(q5.z), "+v"(q5.w));
    asm volatile("" : "+v"(q6.x), "+v"(q6.y), "+v"(q6.z), "+v"(q6.w));
    asm volatile("" : "+v"(q7.x), "+v"(q7.y), "+v"(q7.z), "+v"(q7.w));
  }
  for (int i = tid; i < 2 * 288; i += 512) ((float*)hs)[i] = 0.f;
  float c = 0.f;
  float xv = 0.f;
  if (kc == 0) xv = xpD[(size_t)(dir ? (Tn - 1) : 0) * 2048 + gr];
  const int isprod = ((lane & 31) == 0);
  const int base = lane & 32;
  // consumer role: thread tid<256 polls remote slot `tid` of OUR direction,
  // unless that element belongs to this WG (self-staged by its producer).
  const int iscons = (tid < 256) && ((tid >> 4) != wg);
  const int coff = ((tid & 255) >> 5) * 36 + (tid & 31);   // consumer LDS offset
  const int poff = (he >> 5) * 36 + (he & 31);             // producer LDS offset
  __syncthreads();  // init barrier

  for (int t = 0; t < Tn; ++t) {
    const int p = t & 1;
    // matvec on hs[p] = h(t-1)
    const float4* h4 = (const float4*)&hs[p][kc * 36];
    const float4 h0 = h4[0], h1 = h4[1], h2 = h4[2], h3 = h4[3];
    const float4 h5 = h4[4], h6 = h4[5], h7 = h4[6], h8 = h4[7];
    float a = 0.f;
    a = fmaf(q0.x, h0.x, a); a = fmaf(q0.y, h0.y, a); a = fmaf(q0.z, h0.z, a); a = fmaf(q0.w, h0.w, a);
    a = fmaf(q1.x, h1.x, a); a = fmaf(q1.y, h1.y, a); a = fmaf(q1.z, h1.z, a); a = fmaf(q1.w, h1.w, a);
    a = fmaf(q2.x, h2.x, a); a = fmaf(q2.y, h2.y, a); a = fmaf(q2.z, h2.z, a); a = fmaf(q2.w, h2.w, a);
    a = fmaf(q3.x, h3.x, a); a = fmaf(q3.y, h3.y, a); a = fmaf(q3.z, h3.z, a); a = fmaf(q3.w, h3.w, a);
    a = fmaf(q4.x, h5.x, a); a = fmaf(q4.y, h5.y, a); a = fmaf(q4.z, h5.z, a); a = fmaf(q4.w, h5.w, a);
    a = fmaf(q5.x, h6.x, a); a = fmaf(q5.y, h6.y, a); a = fmaf(q5.z, h6.z, a); a = fmaf(q5.w, h6.w, a);
    a = fmaf(q6.x, h7.x, a); a = fmaf(q6.y, h7.y, a); a = fmaf(q6.z, h7.z, a); a = fmaf(q6.w, h7.w, a);
    a = fmaf(q7.x, h8.x, a); a = fmaf(q7.y, h8.y, a); a = fmaf(q7.z, h8.z, a); a = fmaf(q7.w, h8.w, a);
    a += __shfl_xor(a, 1);
    a += __shfl_xor(a, 2);
    a += __shfl_xor(a, 4);
    if (kc == 0) a += xv;   // xproj (+both biases) folded in by gemm_rows
    // gather the 4 gate sums of this wave's two elements to lanes 0 / 32
    const float gi = __shfl(a, base + 0);
    const float gf = __shfl(a, base + 8);
    const float gg = __shfl(a, base + 16);
    const float go = __shfl(a, base + 24);
    if (isprod) {
      const float iv = 1.f / (1.f + __expf(-gi));
      const float fv = 1.f / (1.f + __expf(-gf));
      const float gv = 1.f - 2.f / (1.f + __expf(2.f * gg));
      const float ov = 1.f / (1.f + __expf(-go));
      c = fv * c + iv * gv;
      const float hv = ov * (1.f - 2.f / (1.f + __expf(2.f * c)));
      // remote-visible word first (critical path)
      __hip_atomic_store(&ex[(size_t)t * 512 + dir * 256 + he],
                         ((unsigned long long)(stampbase + t + 1) << 32) | __float_as_uint(hv),
                         __ATOMIC_RELAXED, __HIP_MEMORY_SCOPE_AGENT);
      // self-stage into the next buffer (no LLC round trip for own elems)
      hs[p ^ 1][poff] = hv;
      const int rowt = dir ? (Tn - 1 - t) : t;
      hcat[(size_t)rowt * 512 + dir * 256 + he] = hv;
    }
    if (t + 1 < Tn) {
      if (kc == 0)  // prefetch next step's xproj (issues before the poll)
        xv = xpD[(size_t)(dir ? (Tn - 2 - t) : (t + 1)) * 2048 + gr];
      if (iscons) {
        const unsigned long long* slot = &ex[(size_t)t * 512 + dir * 256 + tid];
        const unsigned tgt = stampbase + (unsigned)t + 1u;
        unsigned long long v;
        int gd = 0;
        do {
          v = __hip_atomic_load(slot, __ATOMIC_RELAXED, __HIP_MEMORY_SCOPE_AGENT);
        } while ((unsigned)(v >> 32) != tgt && ++gd < (1 << 20));
        hs[p ^ 1][coff] = __uint_as_float((unsigned)v);
      }
    }
    __syncthreads();  // h(t) staged; also protects hs[p] reads vs next overwrite
  }
}

// ---- final 1024->7 matmul + softmax per timestep ----
__global__ __launch_bounds__(64) void mlp2_k(const float* __restrict__ h1,
                                             const float* __restrict__ w2,
                                             const float* __restrict__ b2,
                                             float* __restrict__ out) {
  __shared__ float hrow[1024];
  __shared__ float lg[8];
  const int t = blockIdx.x, tid = threadIdx.x;
  for (int i = tid; i < 1024; i += 64) hrow[i] = h1[(size_t)t * 1024 + i];
  __syncthreads();
  const int o = tid >> 3, kc = tid & 7;
  float acc = 0.f;
  if (o < 7) {
    const float* wv = w2 + (size_t)o * 1024 + kc * 128;
    const float* h = &hrow[kc * 128];
    for (int jj = 0; jj < 128; jj++) acc = fmaf(wv[jj], h[jj], acc);
  }
#pragma unroll
  for (int off = 1; off < 8; off <<= 1) acc += __shfl_xor(acc, off);
  if (o < 7 && kc == 0) lg[o] = acc + b2[o];
  __syncthreads();
  if (tid == 0) {
    float mx = -1e30f;
#pragma unroll
    for (int i = 0; i < 7; i++) mx = fmaxf(mx, lg[i]);
    float e[7];
    float s = 0.f;
#pragma unroll
    for (int i = 0; i < 7; i++) { e[i] = __expf(lg[i] - mx); s += e[i]; }
    const float inv = 1.f / s;
#pragma unroll
    for (int i = 0; i < 7; i++) out[t * 7 + i] = e[i] * inv;
  }
}

extern "C" void kernel_launch(void* const* d_in, const int* in_sizes, int n_in,
                              void* d_out, int out_size, void* d_ws, size_t ws_size,
                              hipStream_t stream) {
  const int* ids = (const int*)d_in[0];
  const float* tab = (const float*)d_in[1];
  const float* wih = (const float*)d_in[2];   // (2,2,1024,512)
  const float* whh = (const float*)d_in[3];   // (2,2,1024,256)
  const float* bih = (const float*)d_in[4];   // (2,2,1024)
  const float* bhh = (const float*)d_in[5];
  const float* w1 = (const float*)d_in[6];    // (1024,512)
  const float* b1 = (const float*)d_in[7];
  const float* w2 = (const float*)d_in[8];    // (7,1024)
  const float* b2 = (const float*)d_in[9];
  float* out = (float*)d_out;                 // (200,7) f32
  float* ws = (float*)d_ws;

  float* x0 = ws;                     // 200*512
  float* xp = ws + 102400;            // 200*2048 (reused both layers)
  float* h0 = ws + 512000;            // 200*512
  float* h1 = ws + 614400;            // 200*512
  float* hm = ws + 716800;            // 200*1024
  unsigned long long* ex = (unsigned long long*)(ws + 921600);  // 200*512 8B slots

  // clear stamps from previous replay (slots are write-once within a launch)
  hipMemsetAsync(ex, 0, (size_t)Tn * 512 * 8, stream);
  embed_k<<<Tn, 128, 0, stream>>>(ids, tab, x0);
  // layer 0
  gemm_rows<<<dim3(8, 25), 256, 0, stream>>>(x0, wih, bih, bhh, xp, 2048, 0);
  rec_k<<<32, 512, 0, stream>>>(xp, h0, ex, whh, 0u);
  // layer 1 (shared ex buffer, disjoint stamp base)
  gemm_rows<<<dim3(8, 25), 256, 0, stream>>>(h0, wih + 1048576, bih + 2048, bhh + 2048, xp, 2048, 0);
  rec_k<<<32, 512, 0, stream>>>(xp, h1, ex, whh + 524288, 1000000u);
  // MLP
  gemm_rows<<<dim3(4, 25), 256, 0, stream>>>(h1, w1, b1, nullptr, hm, 1024, 1);
  mlp2_k<<<Tn, 64, 0, stream>>>(hm, w2, b2, out);
}